// Round 3
// baseline (137.070 us; speedup 1.0000x reference)
//
#include <hip/hip_runtime.h>
#include <hip/hip_cooperative_groups.h>

namespace cg = cooperative_groups;

#define N_NODES 16384
#define N_EDGES 262144
#define DIM 256
#define NBLK 256
#define NTHR 256

typedef __attribute__((ext_vector_type(4))) float f32x4;
typedef __attribute__((ext_vector_type(8))) short bf16x8;

__device__ inline short f2bf(float f) {
    union { float f; unsigned u; } v; v.f = f;
    unsigned r = v.u + 0x7fffu + ((v.u >> 16) & 1u);   // round-to-nearest-even
    return (short)(r >> 16);
}

// ws: deg[16384]u32 | count | srcflag[16384]u8 | list int2[262144] | Wt bf16[256*256] | h f32[16384*256]

__global__ __launch_bounds__(256, 1) void k_fused(
        const float* __restrict__ x, const float* __restrict__ W,
        const float* __restrict__ b, const int* __restrict__ ei,
        const int* __restrict__ sec,
        unsigned* deg, unsigned* count, unsigned char* srcflag,
        int2* list, short* Wt, float* h, float* out) {
    cg::grid_group grid = cg::this_grid();
    const int tid = threadIdx.x;
    const int g = blockIdx.x * NTHR + tid;        // 0..65535

    // ---------------- phase 0: init (deg, srcflag, count, Wt transpose) ----
    {
        int n = g >> 8, k = g & 255;
        Wt[g] = f2bf(W[k * 256 + n]);             // Wt[n][k] = W[k][n]
        if (g < N_NODES) { deg[g] = 1u; srcflag[g] = 0; }
        if (g == 0) *count = 0u;
    }
    grid.sync();

    // ---------------- phase 1: edge filter + compact + degree ---------------
    #pragma unroll
    for (int it = 0; it < N_EDGES / (NBLK * NTHR); ++it) {
        int e = g + it * NBLK * NTHR;
        int r = ei[e];                 // message source
        int c = ei[N_EDGES + e];       // message target
        if (sec[r] == sec[c]) {
            atomicAdd(&deg[c], 1u);
            srcflag[r] = 1;
            unsigned pos = atomicAdd(count, 1u);
            list[pos] = make_int2(r, c);
        }
    }
    grid.sync();

    // ---------------- phase 2: h = x@W (bf16 MFMA), out = h/deg + b ---------
    {
        const int lane = tid & 63;
        const int wave = tid >> 6;
        const int r16  = lane & 15;    // A row / C col within 16-tile
        const int kg   = lane >> 4;    // k-group
        const int bm   = blockIdx.x * 64 + wave * 16;

        const float* xrow = x + (size_t)(bm + r16) * DIM + kg * 8;
        const short* wp   = Wt + r16 * DIM + kg * 8;

        f32x4 acc[16];
        #pragma unroll
        for (int i = 0; i < 16; ++i) acc[i] = (f32x4)0.f;

        f32x4 nx0 = *reinterpret_cast<const f32x4*>(xrow);
        f32x4 nx1 = *reinterpret_cast<const f32x4*>(xrow + 4);
        #pragma unroll
        for (int ks = 0; ks < 8; ++ks) {
            f32x4 c0 = nx0, c1 = nx1;
            if (ks < 7) {
                nx0 = *reinterpret_cast<const f32x4*>(xrow + (ks + 1) * 32);
                nx1 = *reinterpret_cast<const f32x4*>(xrow + (ks + 1) * 32 + 4);
            }
            bf16x8 a;
            #pragma unroll
            for (int j = 0; j < 4; ++j) { a[j] = f2bf(c0[j]); a[4 + j] = f2bf(c1[j]); }
            #pragma unroll
            for (int nf = 0; nf < 16; ++nf) {
                bf16x8 bv = *reinterpret_cast<const bf16x8*>(wp + nf * 16 * DIM + ks * 32);
                acc[nf] = __builtin_amdgcn_mfma_f32_16x16x32_bf16(a, bv, acc[nf], 0, 0, 0);
            }
        }

        // C/D: col = lane&15, row = kg*4 + r
        const int rbase = bm + kg * 4;
        uint4 dv = *reinterpret_cast<const uint4*>(deg + rbase);
        unsigned sf4 = *reinterpret_cast<const unsigned*>(srcflag + rbase);
        float inv[4] = {1.f / (float)dv.x, 1.f / (float)dv.y,
                        1.f / (float)dv.z, 1.f / (float)dv.w};
        #pragma unroll
        for (int nf = 0; nf < 16; ++nf) {
            int n = nf * 16 + r16;
            float bn = b[n];
            #pragma unroll
            for (int r = 0; r < 4; ++r)
                out[(size_t)(rbase + r) * DIM + n] = acc[nf][r] * inv[r] + bn;
        }
        #pragma unroll
        for (int r = 0; r < 4; ++r) {
            if ((sf4 >> (8 * r)) & 1) {          // only active source rows
                #pragma unroll
                for (int nf = 0; nf < 16; ++nf)
                    h[(size_t)(rbase + r) * DIM + nf * 16 + r16] = acc[nf][r];
            }
        }
    }
    grid.sync();

    // ---------------- phase 3: scatter active edges -------------------------
    {
        unsigned nact = *count;
        unsigned wv   = g >> 6;
        unsigned lane = tid & 63;
        for (unsigned e = wv; e < nact; e += (NBLK * NTHR) / 64) {
            int2 rc = list[e];
            float norm = rsqrtf((float)deg[rc.x]) * rsqrtf((float)deg[rc.y]);
            f32x4 hv = *reinterpret_cast<const f32x4*>(&h[(size_t)rc.x * DIM + lane * 4]);
            float* o = &out[(size_t)rc.y * DIM + lane * 4];
            atomicAdd(o + 0, hv[0] * norm);
            atomicAdd(o + 1, hv[1] * norm);
            atomicAdd(o + 2, hv[2] * norm);
            atomicAdd(o + 3, hv[3] * norm);
        }
    }
}

extern "C" void kernel_launch(void* const* d_in, const int* in_sizes, int n_in,
                              void* d_out, int out_size, void* d_ws, size_t ws_size,
                              hipStream_t stream) {
    const float* x  = (const float*)d_in[0];
    const float* W  = (const float*)d_in[1];
    const float* b  = (const float*)d_in[2];
    const int* ei   = (const int*)d_in[3];
    const int* sec  = (const int*)d_in[4];
    float* out      = (float*)d_out;

    char* ws = (char*)d_ws;
    unsigned* deg        = (unsigned*)ws;                     // 64 KB
    unsigned* count      = (unsigned*)(ws + 65536);
    unsigned char* sflag = (unsigned char*)(ws + 65792);      // 16 KB
    int2* list           = (int2*)(ws + 82176);               // 2 MB
    short* Wt            = (short*)(ws + 2179328);            // 128 KB
    float* h             = (float*)(ws + 2310400);            // 16 MB

    void* args[] = {(void*)&x, (void*)&W, (void*)&b, (void*)&ei, (void*)&sec,
                    (void*)&deg, (void*)&count, (void*)&sflag, (void*)&list,
                    (void*)&Wt, (void*)&h, (void*)&out};
    hipLaunchCooperativeKernel((const void*)k_fused, dim3(NBLK), dim3(NTHR),
                               args, 0, stream);
}

// Round 4
// 58.527 us; speedup vs baseline: 2.3420x; 2.3420x over previous
//
#include <hip/hip_runtime.h>

#define N_NODES 16384
#define N_EDGES 262144
#define DIM 256

typedef __attribute__((ext_vector_type(4))) float f32x4;
typedef __attribute__((ext_vector_type(8))) short bf16x8;

__device__ inline short f2bf(float f) {
    union { float f; unsigned u; } v; v.f = f;
    unsigned r = v.u + 0x7fffu + ((v.u >> 16) & 1u);   // round-to-nearest-even
    return (short)(r >> 16);
}

// ws: deg[16384]u32 | count | srcflag[16384]u8 | list int2[262144] | Wt bf16[65536] | h f32[16384*256]

__global__ void k_prep(const float* __restrict__ W, short* __restrict__ Wt,
                       unsigned* __restrict__ deg, unsigned char* __restrict__ srcflag,
                       unsigned* __restrict__ count) {
    int bid = blockIdx.x;
    int tid = threadIdx.x;
    if (bid < 256) {
        int idx = bid * 256 + tid;
        int n = idx >> 8, k = idx & 255;
        Wt[idx] = f2bf(W[k * 256 + n]);   // Wt[n][k] = W[k][n]
    } else {
        int i = (bid - 256) * 256 + tid;
        deg[i] = 1u;
        srcflag[i] = 0;
        if (i == 0) *count = 0u;
    }
}

__global__ void k_edges(const int* __restrict__ ei, const int* __restrict__ sec,
                        unsigned* __restrict__ deg, unsigned char* __restrict__ srcflag,
                        unsigned* __restrict__ count, int2* __restrict__ list) {
    int e = blockIdx.x * blockDim.x + threadIdx.x;
    if (e >= N_EDGES) return;
    int r = ei[e];             // message source
    int c = ei[N_EDGES + e];   // message target
    if (sec[r] == sec[c]) {
        atomicAdd(&deg[c], 1u);
        srcflag[r] = 1;
        unsigned pos = atomicAdd(count, 1u);
        list[pos] = make_int2(r, c);
    }
}

// h = x@W (bf16 MFMA, f32 accum); out = h/deg + b; h stored only for active
// source rows. Each wave: 16 rows x 64 cols. 1024 blocks (4 blocks/CU,
// 16 waves/CU). XCD-grouped mapping: the 4 col-blocks sharing one 64-row
// x panel land on the same XCD's L2.
__global__ __launch_bounds__(256) void k_gemm(
        const float* __restrict__ x, const short* __restrict__ Wt,
        const float* __restrict__ b, const unsigned* __restrict__ deg,
        const unsigned char* __restrict__ srcflag,
        float* __restrict__ h, float* __restrict__ out) {
    const int L   = blockIdx.x;
    const int xcd = L & 7;
    const int li  = L >> 3;                // 0..127
    const int rb  = xcd * 32 + (li >> 2);  // row block 0..255
    const int cb  = li & 3;                // col quarter

    const int tid  = threadIdx.x;
    const int lane = tid & 63;
    const int wave = tid >> 6;
    const int r16  = lane & 15;
    const int kg   = lane >> 4;
    const int bm   = rb * 64 + wave * 16;
    const int bn   = cb * 64;

    const float* xrow = x + (size_t)(bm + r16) * DIM + kg * 8;
    const short* wp   = Wt + (size_t)(bn + r16) * DIM + kg * 8;

    f32x4 acc[4];
    #pragma unroll
    for (int i = 0; i < 4; ++i) acc[i] = (f32x4)0.f;

    f32x4 nx0 = *reinterpret_cast<const f32x4*>(xrow);
    f32x4 nx1 = *reinterpret_cast<const f32x4*>(xrow + 4);
    #pragma unroll
    for (int ks = 0; ks < 8; ++ks) {
        f32x4 c0 = nx0, c1 = nx1;
        if (ks < 7) {
            nx0 = *reinterpret_cast<const f32x4*>(xrow + (ks + 1) * 32);
            nx1 = *reinterpret_cast<const f32x4*>(xrow + (ks + 1) * 32 + 4);
        }
        bf16x8 a;
        #pragma unroll
        for (int j = 0; j < 4; ++j) { a[j] = f2bf(c0[j]); a[4 + j] = f2bf(c1[j]); }
        #pragma unroll
        for (int nf = 0; nf < 4; ++nf) {
            bf16x8 bv = *reinterpret_cast<const bf16x8*>(wp + nf * 16 * DIM + ks * 32);
            acc[nf] = __builtin_amdgcn_mfma_f32_16x16x32_bf16(a, bv, acc[nf], 0, 0, 0);
        }
    }

    // C/D layout: col = lane&15, row = kg*4 + r
    const int rbase = bm + kg * 4;
    uint4 dv = *reinterpret_cast<const uint4*>(deg + rbase);
    unsigned sf4 = *reinterpret_cast<const unsigned*>(srcflag + rbase);
    float inv[4] = {1.f / (float)dv.x, 1.f / (float)dv.y,
                    1.f / (float)dv.z, 1.f / (float)dv.w};
    #pragma unroll
    for (int nf = 0; nf < 4; ++nf) {
        int n = bn + nf * 16 + r16;
        float bn_ = b[n];
        #pragma unroll
        for (int r = 0; r < 4; ++r)
            out[(size_t)(rbase + r) * DIM + n] = acc[nf][r] * inv[r] + bn_;
    }
    #pragma unroll
    for (int r = 0; r < 4; ++r) {
        if ((sf4 >> (8 * r)) & 1) {
            #pragma unroll
            for (int nf = 0; nf < 4; ++nf)
                h[(size_t)(rbase + r) * DIM + bn + nf * 16 + r16] = acc[nf][r];
        }
    }
}

// one wave per active edge; lane l handles dims [4l, 4l+4)
__global__ void k_scatter(const float* __restrict__ h, const unsigned* __restrict__ deg,
                          const unsigned* __restrict__ count, const int2* __restrict__ list,
                          float* __restrict__ out) {
    unsigned nact = *count;
    unsigned wv     = (blockIdx.x * blockDim.x + threadIdx.x) >> 6;
    unsigned lane   = threadIdx.x & 63;
    unsigned nwaves = (gridDim.x * blockDim.x) >> 6;
    for (unsigned e = wv; e < nact; e += nwaves) {
        int2 rc = list[e];
        float norm = rsqrtf((float)deg[rc.x]) * rsqrtf((float)deg[rc.y]);
        f32x4 hv = *reinterpret_cast<const f32x4*>(&h[(size_t)rc.x * DIM + lane * 4]);
        float* o = &out[(size_t)rc.y * DIM + lane * 4];
        atomicAdd(o + 0, hv[0] * norm);
        atomicAdd(o + 1, hv[1] * norm);
        atomicAdd(o + 2, hv[2] * norm);
        atomicAdd(o + 3, hv[3] * norm);
    }
}

extern "C" void kernel_launch(void* const* d_in, const int* in_sizes, int n_in,
                              void* d_out, int out_size, void* d_ws, size_t ws_size,
                              hipStream_t stream) {
    const float* x  = (const float*)d_in[0];
    const float* W  = (const float*)d_in[1];
    const float* b  = (const float*)d_in[2];
    const int* ei   = (const int*)d_in[3];
    const int* sec  = (const int*)d_in[4];
    float* out      = (float*)d_out;

    char* ws = (char*)d_ws;
    unsigned* deg        = (unsigned*)ws;                     // 64 KB
    unsigned* count      = (unsigned*)(ws + 65536);
    unsigned char* sflag = (unsigned char*)(ws + 65792);      // 16 KB
    int2* list           = (int2*)(ws + 82176);               // 2 MB
    short* Wt            = (short*)(ws + 2179328);            // 128 KB
    float* h             = (float*)(ws + 2310400);            // 16 MB

    k_prep<<<320, 256, 0, stream>>>(W, Wt, deg, sflag, count);
    k_edges<<<N_EDGES / 256, 256, 0, stream>>>(ei, sec, deg, sflag, count, list);
    k_gemm<<<1024, 256, 0, stream>>>(x, Wt, b, deg, sflag, h, out);
    k_scatter<<<256, 256, 0, stream>>>(h, deg, count, list, out);
}